// Round 19
// baseline (740.474 us; speedup 1.0000x reference)
//
#include <hip/hip_runtime.h>

typedef __bf16 bf16x8 __attribute__((ext_vector_type(8)));
typedef float f32x4 __attribute__((ext_vector_type(4)));
typedef float f32x4u __attribute__((ext_vector_type(4), aligned(4)));

union Frag {
    uint4 u4;
    bf16x8 b;
    unsigned short s[8];
};

__device__ __forceinline__ float b2f(unsigned int u) {
    return __uint_as_float((u & 0xffffu) << 16);
}
__device__ __forceinline__ unsigned short f2b(float f) {
    unsigned int x = __float_as_uint(f);
    unsigned int r = x + 0x7fffu + ((x >> 16) & 1u);  // RNE
    return (unsigned short)(r >> 16);
}
// HW packed f32->bf16 (RNE), lo=first arg. No builtin on gfx950 -> inline asm
// (non-volatile, register-only: scheduler can move/CSE it freely).
__device__ __forceinline__ unsigned int cvtpk(float lo, float hi) {
    unsigned int r;
    asm("v_cvt_pk_bf16_f32 %0, %1, %2" : "=v"(r) : "v"(lo), "v"(hi));
    return r;
}

// ===========================================================================
// Weight conversion: fp32 -> bf16 hi + bf16 lo (w ≈ hi + lo to ~2^-18 rel)
// ===========================================================================
struct WPtrs {
    const float *bqkv, *bproj, *bfc1, *bfc2, *gqkv, *gproj, *gfc1, *gfc2;
};
__global__ __launch_bounds__(256) void conv_w2(WPtrs p, unsigned short* __restrict__ hi,
                                               unsigned short* __restrict__ lo) {
    int t = blockIdx.x * 256 + threadIdx.x;      // 393216 total
    float v;
    if (t < 49152)       v = p.bqkv[t];
    else if (t < 65536)  v = p.bproj[t - 49152];
    else if (t < 131072) v = p.bfc1[t - 65536];
    else if (t < 196608) v = p.bfc2[t - 131072];
    else if (t < 245760) v = p.gqkv[t - 196608];
    else if (t < 262144) v = p.gproj[t - 245760];
    else if (t < 327680) v = p.gfc1[t - 262144];
    else                 v = p.gfc2[t - 327680];
    unsigned short h = f2b(v);
    hi[t] = h;
    lo[t] = f2b(v - b2f(h));
}

// Per-head contiguous grid-bias table, pre-scaled by 1/sqrt(32) (C-operand).
__global__ __launch_bounds__(256) void conv_bias(const float* __restrict__ table,
                                                 float* __restrict__ tp) {
    int t = blockIdx.x * 256 + threadIdx.x;      // 15876 total
    if (t >= 15876) return;
    int h = t / 3969;
    int idx = t - h * 3969;
    tp[h * 3972 + idx] = table[idx * 4 + h] * 0.17677669529663689f;
}

// window_partition(x,7,7): fp32 x[1,128,224,224] -> bf16 xa[win*49+n][c]
__global__ __launch_bounds__(256) void gather_in(const float* __restrict__ x,
                                                 unsigned short* __restrict__ xa) {
    int t = blockIdx.x * 256 + threadIdx.x;       // 6422528
    int c = t & 127;
    int wn = t >> 7;
    int n = wn % 49;
    int w = wn / 49;
    int i = w >> 5, j = w & 31;
    int p = n / 7, q = n - p * 7;
    xa[t] = f2b(x[(size_t)c * 50176 + (i * 7 + p) * 224 + (j * 7 + q)]);
}

// ===========================================================================
// MFMA GEMM v3: 256x64 block, 64 rows/wave (acc[4][4]) so each B-fragment
// ds_read feeds 4 MFMAs (halves LDS-read per FLOP vs v2). B staged with
// global_load_lds width=16 into LINEAR LDS; bank conflicts on the fragment
// reads removed by XOR swizzle  phys_byte = row*256 + (col_byte ^ ((row&7)<<4))
// applied on the per-lane GLOBAL source (inverse==same, involution) and on
// the ds_read address (both-sides swizzle; LDS dest stays linear as required
// by global_load_lds's wave-uniform-base+lane*16 semantics).
// ===========================================================================
__global__ __launch_bounds__(256) void gemm_bt(const unsigned short* __restrict__ X,
                                               const unsigned short* __restrict__ Whi,
                                               const unsigned short* __restrict__ Wlo,
                                               const float* __restrict__ bias,
                                               const float* __restrict__ resf,
                                               const float* __restrict__ resx,
                                               unsigned short* __restrict__ Yb,
                                               float* __restrict__ Yf,
                                               int M, int N, int K) {
    __shared__ __align__(16) unsigned short sBh[64 * 128];   // 16 KB, linear+swizzled
    __shared__ __align__(16) unsigned short sBl[64 * 128];   // 16 KB
    const int tid = threadIdx.x;
    const int lane = tid & 63;
    const int wid = tid >> 6;
    const int m0 = blockIdx.y * 256 + wid * 64;
    const int n0 = blockIdx.x * 64;
    const int r = lane & 15, g = lane >> 4;

    f32x4 acc[4][4];
#pragma unroll
    for (int i = 0; i < 4; i++)
#pragma unroll
        for (int j = 0; j < 4; j++) acc[i][j] = (f32x4){0.f, 0.f, 0.f, 0.f};

    const unsigned short* xa = X + (size_t)(m0 + r) * K + g * 8;

    // read-side swizzle term (in shorts): ((row&7)<<4 bytes) >> 1
    const int xr = (r & 7) << 3;

    // staging: per wave-issue u, wave wid covers LDS bytes
    // [u*4096 + wid*1024, +1024): rows u*16+wid*4+{0..3}, 16B chunk (lane&15).
    unsigned short* lbh = sBh + wid * 512;   // shorts
    unsigned short* lbl = sBl + wid * 512;

    for (int kt = 0; kt < K; kt += 128) {
        __syncthreads();              // previous tile's B reads done
#pragma unroll
        for (int u = 0; u < 4; ++u) {
            int row = u * 16 + wid * 4 + g;
            int lc = (r * 8) ^ ((row & 7) << 3);   // logical col (shorts), inv-swizzled
            const unsigned short* gh = Whi + (size_t)(n0 + row) * K + kt + lc;
            const unsigned short* gl = Wlo + (size_t)(n0 + row) * K + kt + lc;
            __builtin_amdgcn_global_load_lds(
                (const __attribute__((address_space(1))) void*)gh,
                (__attribute__((address_space(3))) void*)(lbh + u * 2048), 16, 0, 0);
            __builtin_amdgcn_global_load_lds(
                (const __attribute__((address_space(1))) void*)gl,
                (__attribute__((address_space(3))) void*)(lbl + u * 2048), 16, 0, 0);
        }
        __syncthreads();              // staging landed (compiler drains vmcnt)

#pragma unroll
        for (int kc = 0; kc < 128; kc += 32) {
            Frag a[4];
#pragma unroll
            for (int i = 0; i < 4; i++)
                a[i].u4 = *(const uint4*)(xa + (size_t)(i * 16) * K + kt + kc);
#pragma unroll
            for (int j = 0; j < 4; j++) {
                Frag bh, bl;
                const int so = j * 2048 + r * 128 + ((kc + g * 8) ^ xr);
                bh.u4 = *(const uint4*)(sBh + so);
                bl.u4 = *(const uint4*)(sBl + so);
#pragma unroll
                for (int i = 0; i < 4; i++)
                    acc[i][j] = __builtin_amdgcn_mfma_f32_16x16x32_bf16(a[i].b, bh.b, acc[i][j], 0, 0, 0);
#pragma unroll
                for (int i = 0; i < 4; i++)
                    acc[i][j] = __builtin_amdgcn_mfma_f32_16x16x32_bf16(a[i].b, bl.b, acc[i][j], 0, 0, 0);
            }
        }
    }
#pragma unroll
    for (int i = 0; i < 4; i++) {
#pragma unroll
        for (int j = 0; j < 4; j++) {
            int col = n0 + j * 16 + r;
            float bia = bias ? bias[col] : 0.f;
#pragma unroll
            for (int rr = 0; rr < 4; rr++) {
                int rowi = m0 + i * 16 + g * 4 + rr;
                size_t idx = (size_t)rowi * N + col;
                float v = acc[i][j][rr] + bia;
                if (resf) v += resf[idx];
                if (resx) {
                    int w = rowi / 49, n = rowi - w * 49;
                    int ii = w >> 5, jj = w & 31;
                    int p = n / 7, q = n - p * 7;
                    v += resx[(size_t)col * 50176 + (ii * 7 + p) * 224 + (jj * 7 + q)];
                }
                if (Yb) Yb[idx] = f2b(v);
                if (Yf) Yf[idx] = v;
            }
        }
    }
}

// Block attention (7x7, N=49). One block per (window, head). QKV bf16 in.
__global__ __launch_bounds__(256) void attn_block7(const unsigned short* __restrict__ qkv,
                                                   const float* __restrict__ table,
                                                   unsigned short* __restrict__ out) {
    __shared__ __align__(16) unsigned int sq[49 * 17], sk[49 * 17], sv[49 * 17];
    __shared__ float ssc[49 * 49];
    const int bx = blockIdx.x;
    const int w = bx >> 2, h = bx & 3;
    const int tid = threadIdx.x;
    const unsigned int* qsrc = (const unsigned int*)qkv;

    for (int u = tid; u < 784; u += 256) {
        int i = u >> 4, du = u & 15;
        size_t rb = (size_t)(w * 49 + i) * 192 + h * 16 + du;
        sq[i * 17 + du] = qsrc[rb];
        sk[i * 17 + du] = qsrc[rb + 64];
        sv[i * 17 + du] = qsrc[rb + 128];
    }
    __syncthreads();

    for (int e = tid; e < 2401; e += 256) {
        int i = e / 49, j = e - i * 49;
        const unsigned int* qp = sq + i * 17;
        const unsigned int* kp = sk + j * 17;
        float dot = 0.f;
#pragma unroll
        for (int u = 0; u < 16; u++) {
            unsigned int a = qp[u], b = kp[u];
            dot += b2f(a) * b2f(b) + b2f(a >> 16) * b2f(b >> 16);
        }
        int ih = i / 7, iw2 = i - ih * 7, jh = j / 7, jw2 = j - jh * 7;
        int idx = (ih - jh + 6) * 13 + (iw2 - jw2 + 6);
        ssc[e] = dot * 5.65685424949238f + table[idx * 4 + h];
    }
    __syncthreads();

    if (tid < 49) {
        float* row = ssc + tid * 49;
        float mx = -1e30f;
        for (int j = 0; j < 49; j++) mx = fmaxf(mx, row[j]);
        float sum = 0.f;
        for (int j = 0; j < 49; j++) { float p = __expf(row[j] - mx); row[j] = p; sum += p; }
        float inv = 1.f / sum;
        for (int j = 0; j < 49; j++) row[j] *= inv;
    }
    __syncthreads();

    unsigned int* outu = (unsigned int*)out;
    for (int e = tid; e < 784; e += 256) {
        int i = e >> 4, dp = e & 15;
        const float* pr = ssc + i * 49;
        float a0 = 0.f, a1 = 0.f;
        for (int j = 0; j < 49; j++) {
            float p = pr[j];
            unsigned int vv = sv[j * 17 + dp];
            a0 += p * b2f(vv);
            a1 += p * b2f(vv >> 16);
        }
        outu[(size_t)(w * 49 + i) * 64 + h * 16 + dp] =
            (unsigned int)f2b(a0) | ((unsigned int)f2b(a1) << 16);
    }
}

// ===========================================================================
// Grid attention v9 (32x32, N=1024). v8 result: XCD swizzle cut FETCH 107->20MB
// (L2-resident) but dur only 126->113us; MfmaUtil 9.6 / VALU 57 / occ 36.5 ->
// latency/serialization-bound (2 barriers x 16 tiles, short compute per tile).
// v9: 128-key tiles (8 iters): barriers halved, per-tile compute doubled,
// same MFMA count. Bias algebra generalizes (ch 0..7). Frozen-max now over
// first 128 keys (>= accuracy). LDS 35.5KB (>=4 blocks/CU); +16 VGPR prefetch.
// ===========================================================================
__global__ __launch_bounds__(256) void attn_grid32(const unsigned short* __restrict__ qkv,
                                                   const float* __restrict__ tp,
                                                   unsigned short* __restrict__ out) {
    __shared__ __align__(16) unsigned short sK[128][40];
    __shared__ __align__(16) unsigned short sVt[32][136];     // [dim][pos 0..127 +pad]
    __shared__ __align__(16) unsigned short plds[4][16][136]; // [wave][qrow][pos]
    const int tid = threadIdx.x;
    const int lane = tid & 63;
    const int wid = tid >> 6;
    const int b = (blockIdx.x & 7) * 392 + (blockIdx.x >> 3);  // XCD-chunked, bijective
    const int w = b >> 6;
    const int h = (b >> 4) & 3;
    const int qb = b & 15;
    const int q0 = qb * 64 + wid * 16;
    const int c = lane & 15;
    const int g = lane >> 4;
    const size_t base = (size_t)w * 1024 * 384;
    const float scale2 = 5.65685424949238f * 1.4426950408889634f;  // sqrt(32)*log2(e)

    Frag qf;                                   // A-frag: Q[m=c][k=g*8..+7]
    qf.u4 = *(const uint4*)(qkv + base + (size_t)(q0 + c) * 384 + h * 32 + g * 8);

    const int qrow0 = q0 + g * 4;
    const float* tpl = tp + h * 3972 + ((qrow0 >> 5) + 31) * 63 + (qrow0 & 31) + 31 - c;

    float m_[4], l_[4];
    f32x4 o0 = {0.f, 0.f, 0.f, 0.f}, o1 = {0.f, 0.f, 0.f, 0.f};
#pragma unroll
    for (int rr = 0; rr < 4; rr++) { m_[rr] = 0.f; l_[rr] = 0.f; }

    const int skey = lane;
    const int sd = wid * 8;
    const int vpos = 4 * (skey & 15) + (skey >> 4);   // pos(k64) = 4c + ch within half
    const unsigned short* kgp = qkv + base + 128 + h * 32 + sd;
    const unsigned short* vgp = qkv + base + 256 + h * 32 + sd;

    // prefetch tile 0 (two 64-key halves)
    Frag kcur0, kcur1, vcur0, vcur1, knxt0, knxt1, vnxt0, vnxt1;
    kcur0.u4 = *(const uint4*)(kgp + (size_t)skey * 384);
    kcur1.u4 = *(const uint4*)(kgp + (size_t)(skey + 64) * 384);
    vcur0.u4 = *(const uint4*)(vgp + (size_t)skey * 384);
    vcur1.u4 = *(const uint4*)(vgp + (size_t)(skey + 64) * 384);
    knxt0 = kcur0; knxt1 = kcur1; vnxt0 = vcur0; vnxt1 = vcur1;

    for (int jc = 0; jc < 1024; jc += 128) {
        // stage current 128-key tile; prior reads protected by trailing barrier
        *(uint4*)(&sK[skey][sd]) = kcur0.u4;
        *(uint4*)(&sK[skey + 64][sd]) = kcur1.u4;
#pragma unroll
        for (int z = 0; z < 8; ++z) sVt[sd + z][vpos] = vcur0.s[z];
#pragma unroll
        for (int z = 0; z < 8; ++z) sVt[sd + z][64 + vpos] = vcur1.s[z];
        __syncthreads();
        // issue next tile's loads; consumed only after the next barrier
        if (jc < 896) {
            size_t roff = (size_t)(jc + 128 + skey) * 384;
            knxt0.u4 = *(const uint4*)(kgp + roff);
            vnxt0.u4 = *(const uint4*)(vgp + roff);
            knxt1.u4 = *(const uint4*)(kgp + roff + (size_t)64 * 384);
            vnxt1.u4 = *(const uint4*)(vgp + roff + (size_t)64 * 384);
        }

        const float* tpj = tpl - (jc >> 5) * 63;
        f32x4 s4[8];
#pragma unroll
        for (int ch = 0; ch < 8; ++ch) {
            f32x4 cb = (f32x4)(*(const f32x4u*)(tpj - (ch >> 1) * 63 - (ch & 1) * 16));
            Frag kf;
            kf.u4 = *(const uint4*)(&sK[ch * 16 + c][g * 8]);
            s4[ch] = __builtin_amdgcn_mfma_f32_16x16x32_bf16(qf.b, kf.b, cb, 0, 0, 0);
        }
#pragma unroll
        for (int rr = 0; rr < 4; ++rr) {
            if (jc == 0) {
                float cm = fmaxf(fmaxf(fmaxf(s4[0][rr], s4[1][rr]), fmaxf(s4[2][rr], s4[3][rr])),
                                 fmaxf(fmaxf(s4[4][rr], s4[5][rr]), fmaxf(s4[6][rr], s4[7][rr])));
#pragma unroll
                for (int off = 1; off < 16; off <<= 1) cm = fmaxf(cm, __shfl_xor(cm, off, 64));
                m_[rr] = cm * scale2;          // running max kept pre-scaled
            }
            float mn = m_[rr];
            float p0 = exp2f(fmaf(s4[0][rr], scale2, -mn));
            float p1 = exp2f(fmaf(s4[1][rr], scale2, -mn));
            float p2 = exp2f(fmaf(s4[2][rr], scale2, -mn));
            float p3 = exp2f(fmaf(s4[3][rr], scale2, -mn));
            float p4 = exp2f(fmaf(s4[4][rr], scale2, -mn));
            float p5 = exp2f(fmaf(s4[5][rr], scale2, -mn));
            float p6 = exp2f(fmaf(s4[6][rr], scale2, -mn));
            float p7 = exp2f(fmaf(s4[7][rr], scale2, -mn));
            l_[rr] += ((p0 + p1) + (p2 + p3)) + ((p4 + p5) + (p6 + p7));
            unsigned int* prow0 = (unsigned int*)(&plds[wid][g * 4 + rr][c * 4]);
            prow0[0] = cvtpk(p0, p1);
            prow0[1] = cvtpk(p2, p3);
            unsigned int* prow1 = (unsigned int*)(&plds[wid][g * 4 + rr][64 + c * 4]);
            prow1[0] = cvtpk(p4, p5);
            prow1[1] = cvtpk(p6, p7);
        }
#pragma unroll
        for (int ch2 = 0; ch2 < 4; ++ch2) {
            Frag pf, vf0, vf1;
            pf.u4 = *(const uint4*)(&plds[wid][c][ch2 * 32 + g * 8]);
            vf0.u4 = *(const uint4*)(&sVt[c][ch2 * 32 + g * 8]);
            vf1.u4 = *(const uint4*)(&sVt[16 + c][ch2 * 32 + g * 8]);
            o0 = __builtin_amdgcn_mfma_f32_16x16x32_bf16(pf.b, vf0.b, o0, 0, 0, 0);
            o1 = __builtin_amdgcn_mfma_f32_16x16x32_bf16(pf.b, vf1.b, o1, 0, 0, 0);
        }
        __syncthreads();
        kcur0 = knxt0; kcur1 = knxt1; vcur0 = vnxt0; vcur1 = vnxt1;
    }
#pragma unroll
    for (int rr = 0; rr < 4; rr++) {
        float ls = l_[rr];
#pragma unroll
        for (int off = 1; off < 16; off <<= 1) ls += __shfl_xor(ls, off, 64);
        float inv = 1.0f / ls;
        int row = q0 + g * 4 + rr;
        size_t ob = (size_t)(w * 1024 + row) * 128 + h * 32;
        out[ob + c] = f2b(o0[rr] * inv);
        out[ob + 16 + c] = f2b(o1[rr] * inv);
    }
}

// LayerNorm on fp32 input; writes bf16 (GEMM input) + fp32 (MLP shortcut).
__global__ __launch_bounds__(256) void ln_f(const float* __restrict__ in,
                                            const float* __restrict__ gam,
                                            const float* __restrict__ bet,
                                            unsigned short* __restrict__ outb,
                                            float* __restrict__ outf) {
    int token = blockIdx.x * 4 + (threadIdx.x >> 6);
    int lane = threadIdx.x & 63;
    float2 v = ((const float2*)in)[(size_t)token * 64 + lane];
    float s = v.x + v.y, s2 = v.x * v.x + v.y * v.y;
#pragma unroll
    for (int off = 1; off < 64; off <<= 1) {
        s += __shfl_xor(s, off, 64);
        s2 += __shfl_xor(s2, off, 64);
    }
    float mean = s * (1.f / 128.f);
    float var = s2 * (1.f / 128.f) - mean * mean;
    float inv = rsqrtf(var + 1e-5f);
    float2 gv = ((const float2*)gam)[lane];
    float2 bv = ((const float2*)bet)[lane];
    float y0 = (v.x - mean) * inv * gv.x + bv.x;
    float y1 = (v.y - mean) * inv * gv.y + bv.y;
    ((unsigned int*)outb)[(size_t)token * 64 + lane] =
        (unsigned int)f2b(y0) | ((unsigned int)f2b(y1) << 16);
    ((float2*)outf)[(size_t)token * 64 + lane] = make_float2(y0, y1);
}

// unbind(7)+transpose+partition(32): fp32 ya -> bf16 xb + fp32 xbf
__global__ __launch_bounds__(256) void remap_ab_f(const float* __restrict__ ya,
                                                  unsigned short* __restrict__ xb,
                                                  float* __restrict__ xbf) {
    int t = blockIdx.x * 256 + threadIdx.x;
    int c2 = t & 127;
    int tok = (t >> 7) & 1023;
    int W2 = t >> 17;
    int P = tok >> 5, Q = tok & 31;
    int I = W2 / 7, J = W2 - I * 7;
    int y = I * 32 + P, x2 = J * 32 + Q;
    int f = y * 28672 + x2 * 128 + c2;
    int c = f / 50176;
    int rm = f - c * 50176;
    int i = rm / 1568;
    int r2 = rm - i * 1568;
    int p = r2 / 224;
    int r3 = r2 - p * 224;
    int q = r3 >> 5, j = r3 & 31;
    float val = ya[((size_t)((i * 32 + j) * 49 + p * 7 + q)) * 128 + c];
    xb[t] = f2b(val);
    xbf[t] = val;
}

// unbind(32)+final transpose: fp32 yb -> fp32 out[1,128,224,224]
__global__ __launch_bounds__(256) void remap_out_f(const float* __restrict__ yb,
                                                   float* __restrict__ out) {
    int t = blockIdx.x * 256 + threadIdx.x;
    int c2 = t / 50176;
    int rem = t - c2 * 50176;
    int y = rem / 224;
    int x2 = rem - y * 224;
    int g = y * 28672 + x2 * 128 + c2;
    int c = g / 50176;
    int r = g - c * 50176;
    int I = r / 7168;
    int r2 = r - I * 7168;
    int P = r2 / 224;
    int r3 = r2 - P * 224;
    int Q = r3 / 7, J = r3 - Q * 7;
    out[t] = yb[((size_t)((I * 7 + J) * 1024 + P * 32 + Q)) * 128 + c];
}

// ===========================================================================
// FALLBACK PATH (proven round-7 scalar kernels; used if ws_size too small)
// ===========================================================================
__global__ __launch_bounds__(256) void remap_ab_s(const unsigned short* __restrict__ ya,
                                                  unsigned short* __restrict__ xb) {
    int t = blockIdx.x * 256 + threadIdx.x;
    int c2 = t & 127;
    int tok = (t >> 7) & 1023;
    int W2 = t >> 17;
    int P = tok >> 5, Q = tok & 31;
    int I = W2 / 7, J = W2 - I * 7;
    int y = I * 32 + P, x2 = J * 32 + Q;
    int f = y * 28672 + x2 * 128 + c2;
    int c = f / 50176;
    int rm = f - c * 50176;
    int i = rm / 1568;
    int r2 = rm - i * 1568;
    int p = r2 / 224;
    int r3 = r2 - p * 224;
    int q = r3 >> 5, j = r3 & 31;
    xb[t] = ya[((size_t)((i * 32 + j) * 49 + p * 7 + q)) * 128 + c];
}
__global__ __launch_bounds__(256) void remap_out_s(const unsigned short* __restrict__ yb,
                                                   float* __restrict__ out) {
    int t = blockIdx.x * 256 + threadIdx.x;
    int c2 = t / 50176;
    int rem = t - c2 * 50176;
    int y = rem / 224;
    int x2 = rem - y * 224;
    int g = y * 28672 + x2 * 128 + c2;
    int c = g / 50176;
    int r = g - c * 50176;
    int I = r / 7168;
    int r2 = r - I * 7168;
    int P = r2 / 224;
    int r3 = r2 - P * 224;
    int Q = r3 / 7, J = r3 - Q * 7;
    out[t] = b2f(yb[((size_t)((I * 7 + J) * 1024 + P * 32 + Q)) * 128 + c]);
}
__global__ __launch_bounds__(256) void gemm_w32(const unsigned short* __restrict__ X,
                                                const float* __restrict__ W,
                                                const float* __restrict__ bias,
                                                const unsigned short* __restrict__ res,
                                                unsigned short* __restrict__ Y,
                                                int M, int N, int K) {
    long long t = (long long)blockIdx.x * 256 + threadIdx.x;
    if (t >= (long long)M * N) return;
    int m = (int)(t / N);
    int n = (int)(t - (long long)m * N);
    const unsigned short* xr = X + (size_t)m * K;
    const float* wr = W + (size_t)n * K;
    float acc = bias ? bias[n] : 0.f;
    for (int k = 0; k < K; ++k) acc += b2f(xr[k]) * wr[k];
    if (res) acc += b2f(res[t]);
    Y[t] = f2b(acc);
}
__global__ __launch_bounds__(256) void attn_block7_fused(const unsigned short* __restrict__ xa,
                                                         const float* __restrict__ qw,
                                                         const float* __restrict__ table,
                                                         unsigned short* __restrict__ out) {
    __shared__ unsigned short sx[49 * 128];
    __shared__ float sq[49 * 32], sk[49 * 32], sv[49 * 32];
    __shared__ float ssc[49 * 49];
    const int bx = blockIdx.x;
    const int w = bx >> 2, h = bx & 3;
    const int tid = threadIdx.x;
    for (int u = tid; u < 6272; u += 256) sx[u] = xa[(size_t)(w * 49) * 128 + u];
    __syncthreads();
    for (int e = tid; e < 4704; e += 256) {
        int which = e / 1568;
        int rem = e - which * 1568;
        int n = rem >> 5, d = rem & 31;
        const float* wr = qw + (size_t)(which * 128 + h * 32 + d) * 128;
        const unsigned short* xr = sx + n * 128;
        float acc = 0.f;
        for (int k = 0; k < 128; ++k) acc += b2f(xr[k]) * wr[k];
        if (which == 0) sq[n * 32 + d] = acc;
        else if (which == 1) sk[n * 32 + d] = acc;
        else sv[n * 32 + d] = acc;
    }
    __syncthreads();
    for (int e = tid; e < 2401; e += 256) {
        int i = e / 49, j = e - i * 49;
        float dot = 0.f;
        for (int d = 0; d < 32; ++d) dot += sq[i * 32 + d] * sk[j * 32 + d];
        int ih = i / 7, iw2 = i - ih * 7, jh = j / 7, jw2 = j - jh * 7;
        int idx = (ih - jh + 6) * 13 + (iw2 - jw2 + 6);
        ssc[e] = dot * 5.65685424949238f + table[idx * 4 + h];
    }
    __syncthreads();
    if (tid < 49) {
        float* row = ssc + tid * 49;
        float mx = -1e30f;
        for (int j = 0; j < 49; j++) mx = fmaxf(mx, row[j]);
        float sum = 0.f;
        for (int j = 0; j < 49; j++) { float p = __expf(row[j] - mx); row[j] = p; sum += p; }
        float inv = 1.f / sum;
        for (int j = 0; j < 49; j++) row[j] *= inv;
    }
    __syncthreads();
    for (int e = tid; e < 1568; e += 256) {
        int i = e >> 5, d = e & 31;
        const float* pr = ssc + i * 49;
        float a = 0.f;
        for (int j = 0; j < 49; j++) a += pr[j] * sv[j * 32 + d];
        out[(size_t)(w * 49 + i) * 128 + h * 32 + d] = f2b(a);
    }
}
__global__ __launch_bounds__(256) void kv_head(const unsigned short* __restrict__ xa,
                                               const float* __restrict__ qw,
                                               int h,
                                               unsigned short* __restrict__ kvh) {
    int t = blockIdx.x * 256 + threadIdx.x;
    int tok = t >> 6, e = t & 63;
    int which = (e < 32) ? 1 : 2;
    int d = e & 31;
    const float* wr = qw + (size_t)(which * 128 + h * 32 + d) * 128;
    const unsigned short* xr = xa + (size_t)tok * 128;
    float acc = 0.f;
    for (int k = 0; k < 128; ++k) acc += b2f(xr[k]) * wr[k];
    kvh[t] = f2b(acc);
}
__global__ __launch_bounds__(256) void attn_grid_head(const unsigned short* __restrict__ xa,
                                                      const unsigned short* __restrict__ kvh,
                                                      const float* __restrict__ qw,
                                                      const float* __restrict__ table,
                                                      int h,
                                                      unsigned short* __restrict__ out) {
    __shared__ float sq[32];
    __shared__ float ss[1024];
    __shared__ float red[256];
    __shared__ float pvp[256];
    const int w = blockIdx.x >> 4;
    const int qg = blockIdx.x & 15;
    const int tid = threadIdx.x;
    const float scale = 5.65685424949238f;
    for (int qq = 0; qq < 64; ++qq) {
        const int qi = qg * 64 + qq;
        const int tok = w * 1024 + qi;
        if (tid < 32) {
            const float* wr = qw + (size_t)(h * 32 + tid) * 128;
            const unsigned short* xr = xa + (size_t)tok * 128;
            float acc = 0.f;
            for (int k = 0; k < 128; ++k) acc += b2f(xr[k]) * wr[k];
            sq[tid] = acc;
        }
        __syncthreads();
        const int ihq = qi >> 5, iwq = qi & 31;
        for (int k = tid; k < 1024; k += 256) {
            const unsigned short* kp = kvh + (size_t)(w * 1024 + k) * 64;
            float dot = 0.f;
            for (int d = 0; d < 32; ++d) dot += sq[d] * b2f(kp[d]);
            int jh2 = k >> 5, jw2 = k & 31;
            int idx = (ihq - jh2 + 31) * 63 + (iwq - jw2 + 31);
            ss[k] = dot * scale + table[idx * 4 + h];
        }
        __syncthreads();
        float m = fmaxf(fmaxf(ss[tid], ss[tid + 256]), fmaxf(ss[tid + 512], ss[tid + 768]));
        red[tid] = m;
        __syncthreads();
        for (int s = 128; s > 0; s >>= 1) {
            if (tid < s) red[tid] = fmaxf(red[tid], red[tid + s]);
            __syncthreads();
        }
        m = red[0];
        __syncthreads();
        float ps = 0.f;
        for (int k = tid; k < 1024; k += 256) {
            float p = __expf(ss[k] - m);
            ss[k] = p;
            ps += p;
        }
        red[tid] = ps;
        __syncthreads();
        for (int s = 128; s > 0; s >>= 1) {
            if (tid < s) red[tid] += red[tid + s];
            __syncthreads();
        }
        float l = red[0];
        int kc = tid >> 5, d = tid & 31;
        float a = 0.f;
        const unsigned short* vbase = kvh + (size_t)(w * 1024) * 64 + 32 + d;
        for (int k = kc * 128; k < kc * 128 + 128; ++k) a += ss[k] * b2f(vbase[(size_t)k * 64]);
        pvp[tid] = a;
        __syncthreads();
        if (tid < 32) {
            float o = 0.f;
            for (int c2 = 0; c2 < 8; ++c2) o += pvp[c2 * 32 + tid];
            out[(size_t)tok * 128 + h * 32 + tid] = f2b(o / l);
        }
        __syncthreads();
    }
}
__global__ __launch_bounds__(256) void mlp_fused(const unsigned short* __restrict__ xin,
                                                 const float* __restrict__ fc1w,
                                                 const float* __restrict__ fc1b,
                                                 const float* __restrict__ fc2w,
                                                 const float* __restrict__ fc2b,
                                                 unsigned short* __restrict__ out) {
    __shared__ float sxr[128];
    __shared__ float sh[512];
    const int tok = blockIdx.x;
    const int tid = threadIdx.x;
    if (tid < 128) sxr[tid] = b2f(xin[(size_t)tok * 128 + tid]);
    __syncthreads();
    for (int hh = tid; hh < 512; hh += 256) {
        const float* wr = fc1w + (size_t)hh * 128;
        float acc = fc1b[hh];
        for (int k = 0; k < 128; ++k) acc += sxr[k] * wr[k];
        sh[hh] = acc;
    }
    __syncthreads();
    if (tid < 128) {
        const float* wr = fc2w + (size_t)tid * 512;
        float acc = fc2b[tid];
        for (int k = 0; k < 512; ++k) acc += sh[k] * wr[k];
        out[(size_t)tok * 128 + tid] = f2b(acc + sxr[tid]);
    }
}
__global__ __launch_bounds__(256) void ln_k(const unsigned short* __restrict__ in,
                                            const float* __restrict__ gam,
                                            const float* __restrict__ bet,
                                            unsigned short* __restrict__ out) {
    int token = blockIdx.x * 4 + (threadIdx.x >> 6);
    int lane = threadIdx.x & 63;
    const unsigned int* row = (const unsigned int*)in + (size_t)token * 64;
    unsigned int v = row[lane];
    float x0 = b2f(v), x1 = b2f(v >> 16);
    float s = x0 + x1, s2 = x0 * x0 + x1 * x1;
#pragma unroll
    for (int off = 1; off < 64; off <<= 1) {
        s += __shfl_xor(s, off, 64);
        s2 += __shfl_xor(s2, off, 64);
    }
    float mean = s * (1.f / 128.f);
    float var = s2 * (1.f / 128.f) - mean * mean;
    float inv = rsqrtf(var + 1e-5f);
    float2 gv = ((const float2*)gam)[lane];
    float2 bv = ((const float2*)bet)[lane];
    float y0 = (x0 - mean) * inv * gv.x + bv.x;
    float y1 = (x1 - mean) * inv * gv.y + bv.y;
    ((unsigned int*)out)[(size_t)token * 64 + lane] =
        (unsigned int)f2b(y0) | ((unsigned int)f2b(y1) << 16);
}

// ===========================================================================
extern "C" void kernel_launch(void* const* d_in, const int* in_sizes, int n_in,
                              void* d_out, int out_size, void* d_ws, size_t ws_size,
                              hipStream_t stream) {
    (void)in_sizes; (void)n_in; (void)out_size;
    const float* x = (const float*)d_in[0];
    unsigned short* ws = (unsigned short*)d_ws;
    const int M = 50176;
    dim3 blk(256);
    #define F32(i) ((const float*)d_in[i])

    if (ws_size >= 117178368ull) {
        // ---------------- FAST PATH (MFMA, split weights) ----------------
        unsigned short* WHI = ws;
        unsigned short* WLO = ws + 393216;
        unsigned short* XA  = ws + 786432;
        unsigned short* AT  = ws + 7208960;
        unsigned short* Y2  = ws + 13631488;
        float*          R1  = (float*)(ws + 20054016);
        unsigned short* BIG = ws + 32899072;
        float*          Yf  = (float*)d_out;          // Y1f scratch
        float*          YOB = (float*)XA;             // stage-B fp32 out (XA∪AT)
        float*          TP  = (float*)d_out + 6400000; // grid-bias table (dead window)

        WPtrs wp = {F32(2), F32(3), F32(7), F32(9), F32(12), F32(13), F32(17), F32(19)};
        const size_t oqkv = 0, oproj = 49152, ofc1 = 65536, ofc2 = 131072;
        const size_t goff = 196608;

        conv_w2<<<1536, blk, 0, stream>>>(wp, WHI, WLO);
        gather_in<<<25088, blk, 0, stream>>>(x, XA);

        // ---- stage A ----
        gemm_bt<<<dim3(6, 196), blk, 0, stream>>>(XA, WHI + oqkv, WLO + oqkv, nullptr,
                                                  nullptr, nullptr, BIG, nullptr, M, 384, 128);
        attn_block7<<<4096, blk, 0, stream>>>(BIG, F32(1), AT);
        gemm_bt<<<dim3(2, 196), blk, 0, stream>>>(AT, WHI + oproj, WLO + oproj, F32(4),
                                                  nullptr, x, nullptr, Yf, M, 128, 128);
        ln_f<<<12544, blk, 0, stream>>>(Yf, F32(5), F32(6), Y2, R1);
        gemm_bt<<<dim3(8, 196), blk, 0, stream>>>(Y2, WHI + ofc1, WLO + ofc1, F32(8),
                                                  nullptr, nullptr, BIG, nullptr, M, 512, 128);
        gemm_bt<<<dim3(2, 196), blk, 0, stream>>>(BIG, WHI + ofc2, WLO + ofc2, F32(10),
                                                  R1, nullptr, nullptr, Yf, M, 128, 512);
        remap_ab_f<<<25088, blk, 0, stream>>>(Yf, XA, R1);

        // ---- stage B ----
        conv_bias<<<63, blk, 0, stream>>>(F32(11), TP);  // d_out tail is dead here
        gemm_bt<<<dim3(6, 196), blk, 0, stream>>>(XA, WHI + goff + oqkv, WLO + goff + oqkv,
                                                  nullptr, nullptr, nullptr, BIG, nullptr, M, 384, 128);
        attn_grid32<<<3136, blk, 0, stream>>>(BIG, TP, AT);
        gemm_bt<<<dim3(2, 196), blk, 0, stream>>>(AT, WHI + goff + oproj, WLO + goff + oproj,
                                                  F32(14), R1, nullptr, nullptr, Yf, M, 128, 128);
        ln_f<<<12544, blk, 0, stream>>>(Yf, F32(15), F32(16), Y2, R1);
        gemm_bt<<<dim3(8, 196), blk, 0, stream>>>(Y2, WHI + goff + ofc1, WLO + goff + ofc1,
                                                  F32(18), nullptr, nullptr, BIG, nullptr, M, 512, 128);
        gemm_bt<<<dim3(2, 196), blk, 0, stream>>>(BIG, WHI + goff + ofc2, WLO + goff + ofc2,
                                                  F32(20), R1, nullptr, nullptr, YOB, M, 128, 512);
        remap_out_f<<<25088, blk, 0, stream>>>(YOB, (float*)d_out);
    } else {
        // ---------------- FALLBACK (proven round-7 scalar path) ----------------
        unsigned short* XA  = ws;
        unsigned short* AT  = XA + 6422528;
        unsigned short* KVh = AT + 6422528;
        unsigned short* Yd  = (unsigned short*)d_out;

        gather_in<<<25088, blk, 0, stream>>>(x, XA);
        attn_block7_fused<<<4096, blk, 0, stream>>>(XA, F32(2), F32(1), AT);
        gemm_w32<<<25088, blk, 0, stream>>>(AT, F32(3), F32(4), XA, Yd, M, 128, 128);
        ln_k<<<12544, blk, 0, stream>>>(Yd, F32(5), F32(6), Yd);
        mlp_fused<<<50176, blk, 0, stream>>>(Yd, F32(7), F32(8), F32(9), F32(10), AT);
        remap_ab_s<<<25088, blk, 0, stream>>>(AT, XA);
        for (int h = 0; h < 4; ++h) {
            kv_head<<<12544, blk, 0, stream>>>(XA, F32(12), h, KVh);
            attn_grid_head<<<784, blk, 0, stream>>>(XA, KVh, F32(12), F32(11), h, AT);
        }
        gemm_w32<<<25088, blk, 0, stream>>>(AT, F32(13), F32(14), XA, Yd, M, 128, 128);
        ln_k<<<12544, blk, 0, stream>>>(Yd, F32(15), F32(16), Yd);
        mlp_fused<<<50176, blk, 0, stream>>>(Yd, F32(17), F32(18), F32(19), F32(20), AT);
        remap_out_s<<<25088, blk, 0, stream>>>(AT, (float*)d_out);
    }
    #undef F32
}

// Round 20
// 671.426 us; speedup vs baseline: 1.1028x; 1.1028x over previous
//
#include <hip/hip_runtime.h>

typedef __bf16 bf16x8 __attribute__((ext_vector_type(8)));
typedef float f32x4 __attribute__((ext_vector_type(4)));
typedef float f32x4u __attribute__((ext_vector_type(4), aligned(4)));

union Frag {
    uint4 u4;
    bf16x8 b;
    unsigned short s[8];
};

__device__ __forceinline__ float b2f(unsigned int u) {
    return __uint_as_float((u & 0xffffu) << 16);
}
__device__ __forceinline__ unsigned short f2b(float f) {
    unsigned int x = __float_as_uint(f);
    unsigned int r = x + 0x7fffu + ((x >> 16) & 1u);  // RNE
    return (unsigned short)(r >> 16);
}
// HW packed f32->bf16 (RNE), lo=first arg. No builtin on gfx950 -> inline asm
// (non-volatile, register-only: scheduler can move/CSE it freely).
__device__ __forceinline__ unsigned int cvtpk(float lo, float hi) {
    unsigned int r;
    asm("v_cvt_pk_bf16_f32 %0, %1, %2" : "=v"(r) : "v"(lo), "v"(hi));
    return r;
}

// ===========================================================================
// Weight conversion: fp32 -> bf16 hi + bf16 lo (w ≈ hi + lo to ~2^-18 rel)
// ===========================================================================
struct WPtrs {
    const float *bqkv, *bproj, *bfc1, *bfc2, *gqkv, *gproj, *gfc1, *gfc2;
};
__global__ __launch_bounds__(256) void conv_w2(WPtrs p, unsigned short* __restrict__ hi,
                                               unsigned short* __restrict__ lo) {
    int t = blockIdx.x * 256 + threadIdx.x;      // 393216 total
    float v;
    if (t < 49152)       v = p.bqkv[t];
    else if (t < 65536)  v = p.bproj[t - 49152];
    else if (t < 131072) v = p.bfc1[t - 65536];
    else if (t < 196608) v = p.bfc2[t - 131072];
    else if (t < 245760) v = p.gqkv[t - 196608];
    else if (t < 262144) v = p.gproj[t - 245760];
    else if (t < 327680) v = p.gfc1[t - 262144];
    else                 v = p.gfc2[t - 327680];
    unsigned short h = f2b(v);
    hi[t] = h;
    lo[t] = f2b(v - b2f(h));
}

// Per-head contiguous grid-bias table, pre-scaled by 1/sqrt(32) (C-operand).
__global__ __launch_bounds__(256) void conv_bias(const float* __restrict__ table,
                                                 float* __restrict__ tp) {
    int t = blockIdx.x * 256 + threadIdx.x;      // 15876 total
    if (t >= 15876) return;
    int h = t / 3969;
    int idx = t - h * 3969;
    tp[h * 3972 + idx] = table[idx * 4 + h] * 0.17677669529663689f;
}

// window_partition(x,7,7): fp32 x[1,128,224,224] -> bf16 xa[win*49+n][c]
__global__ __launch_bounds__(256) void gather_in(const float* __restrict__ x,
                                                 unsigned short* __restrict__ xa) {
    int t = blockIdx.x * 256 + threadIdx.x;       // 6422528
    int c = t & 127;
    int wn = t >> 7;
    int n = wn % 49;
    int w = wn / 49;
    int i = w >> 5, j = w & 31;
    int p = n / 7, q = n - p * 7;
    xa[t] = f2b(x[(size_t)c * 50176 + (i * 7 + p) * 224 + (j * 7 + q)]);
}

// ===========================================================================
// MFMA GEMM v3: 256x64 block, 64 rows/wave (acc[4][4]) so each B-fragment
// ds_read feeds 4 MFMAs. B staged with global_load_lds width=16 into LINEAR
// LDS; bank conflicts on fragment reads removed by XOR swizzle (both-sides
// involution; LDS dest stays linear per global_load_lds semantics).
// ===========================================================================
__global__ __launch_bounds__(256) void gemm_bt(const unsigned short* __restrict__ X,
                                               const unsigned short* __restrict__ Whi,
                                               const unsigned short* __restrict__ Wlo,
                                               const float* __restrict__ bias,
                                               const float* __restrict__ resf,
                                               const float* __restrict__ resx,
                                               unsigned short* __restrict__ Yb,
                                               float* __restrict__ Yf,
                                               int M, int N, int K) {
    __shared__ __align__(16) unsigned short sBh[64 * 128];   // 16 KB, linear+swizzled
    __shared__ __align__(16) unsigned short sBl[64 * 128];   // 16 KB
    const int tid = threadIdx.x;
    const int lane = tid & 63;
    const int wid = tid >> 6;
    const int m0 = blockIdx.y * 256 + wid * 64;
    const int n0 = blockIdx.x * 64;
    const int r = lane & 15, g = lane >> 4;

    f32x4 acc[4][4];
#pragma unroll
    for (int i = 0; i < 4; i++)
#pragma unroll
        for (int j = 0; j < 4; j++) acc[i][j] = (f32x4){0.f, 0.f, 0.f, 0.f};

    const unsigned short* xa = X + (size_t)(m0 + r) * K + g * 8;
    const int xr = (r & 7) << 3;
    unsigned short* lbh = sBh + wid * 512;
    unsigned short* lbl = sBl + wid * 512;

    for (int kt = 0; kt < K; kt += 128) {
        __syncthreads();
#pragma unroll
        for (int u = 0; u < 4; ++u) {
            int row = u * 16 + wid * 4 + g;
            int lc = (r * 8) ^ ((row & 7) << 3);
            const unsigned short* gh = Whi + (size_t)(n0 + row) * K + kt + lc;
            const unsigned short* gl = Wlo + (size_t)(n0 + row) * K + kt + lc;
            __builtin_amdgcn_global_load_lds(
                (const __attribute__((address_space(1))) void*)gh,
                (__attribute__((address_space(3))) void*)(lbh + u * 2048), 16, 0, 0);
            __builtin_amdgcn_global_load_lds(
                (const __attribute__((address_space(1))) void*)gl,
                (__attribute__((address_space(3))) void*)(lbl + u * 2048), 16, 0, 0);
        }
        __syncthreads();

#pragma unroll
        for (int kc = 0; kc < 128; kc += 32) {
            Frag a[4];
#pragma unroll
            for (int i = 0; i < 4; i++)
                a[i].u4 = *(const uint4*)(xa + (size_t)(i * 16) * K + kt + kc);
#pragma unroll
            for (int j = 0; j < 4; j++) {
                Frag bh, bl;
                const int so = j * 2048 + r * 128 + ((kc + g * 8) ^ xr);
                bh.u4 = *(const uint4*)(sBh + so);
                bl.u4 = *(const uint4*)(sBl + so);
#pragma unroll
                for (int i = 0; i < 4; i++)
                    acc[i][j] = __builtin_amdgcn_mfma_f32_16x16x32_bf16(a[i].b, bh.b, acc[i][j], 0, 0, 0);
#pragma unroll
                for (int i = 0; i < 4; i++)
                    acc[i][j] = __builtin_amdgcn_mfma_f32_16x16x32_bf16(a[i].b, bl.b, acc[i][j], 0, 0, 0);
            }
        }
    }
#pragma unroll
    for (int i = 0; i < 4; i++) {
#pragma unroll
        for (int j = 0; j < 4; j++) {
            int col = n0 + j * 16 + r;
            float bia = bias ? bias[col] : 0.f;
#pragma unroll
            for (int rr = 0; rr < 4; rr++) {
                int rowi = m0 + i * 16 + g * 4 + rr;
                size_t idx = (size_t)rowi * N + col;
                float v = acc[i][j][rr] + bia;
                if (resf) v += resf[idx];
                if (resx) {
                    int w = rowi / 49, n = rowi - w * 49;
                    int ii = w >> 5, jj = w & 31;
                    int p = n / 7, q = n - p * 7;
                    v += resx[(size_t)col * 50176 + (ii * 7 + p) * 224 + (jj * 7 + q)];
                }
                if (Yb) Yb[idx] = f2b(v);
                if (Yf) Yf[idx] = v;
            }
        }
    }
}

// ===========================================================================
// gemm_bt128: identical math, 128-row blocks (wave covers 32 rows, acc[2][4]).
// For N=128 GEMMs (proj/fc2) whose 392-block launches left ~47% of CUs idle
// in the tail (1.53 blocks/CU); 784 blocks ~= 3/CU.
// ===========================================================================
__global__ __launch_bounds__(256) void gemm_bt128(const unsigned short* __restrict__ X,
                                                  const unsigned short* __restrict__ Whi,
                                                  const unsigned short* __restrict__ Wlo,
                                                  const float* __restrict__ bias,
                                                  const float* __restrict__ resf,
                                                  const float* __restrict__ resx,
                                                  unsigned short* __restrict__ Yb,
                                                  float* __restrict__ Yf,
                                                  int M, int N, int K) {
    __shared__ __align__(16) unsigned short sBh[64 * 128];
    __shared__ __align__(16) unsigned short sBl[64 * 128];
    const int tid = threadIdx.x;
    const int lane = tid & 63;
    const int wid = tid >> 6;
    const int m0 = blockIdx.y * 128 + wid * 32;
    const int n0 = blockIdx.x * 64;
    const int r = lane & 15, g = lane >> 4;

    f32x4 acc[2][4];
#pragma unroll
    for (int i = 0; i < 2; i++)
#pragma unroll
        for (int j = 0; j < 4; j++) acc[i][j] = (f32x4){0.f, 0.f, 0.f, 0.f};

    const unsigned short* xa = X + (size_t)(m0 + r) * K + g * 8;
    const int xr = (r & 7) << 3;
    unsigned short* lbh = sBh + wid * 512;
    unsigned short* lbl = sBl + wid * 512;

    for (int kt = 0; kt < K; kt += 128) {
        __syncthreads();
#pragma unroll
        for (int u = 0; u < 4; ++u) {
            int row = u * 16 + wid * 4 + g;
            int lc = (r * 8) ^ ((row & 7) << 3);
            const unsigned short* gh = Whi + (size_t)(n0 + row) * K + kt + lc;
            const unsigned short* gl = Wlo + (size_t)(n0 + row) * K + kt + lc;
            __builtin_amdgcn_global_load_lds(
                (const __attribute__((address_space(1))) void*)gh,
                (__attribute__((address_space(3))) void*)(lbh + u * 2048), 16, 0, 0);
            __builtin_amdgcn_global_load_lds(
                (const __attribute__((address_space(1))) void*)gl,
                (__attribute__((address_space(3))) void*)(lbl + u * 2048), 16, 0, 0);
        }
        __syncthreads();

#pragma unroll
        for (int kc = 0; kc < 128; kc += 32) {
            Frag a[2];
#pragma unroll
            for (int i = 0; i < 2; i++)
                a[i].u4 = *(const uint4*)(xa + (size_t)(i * 16) * K + kt + kc);
#pragma unroll
            for (int j = 0; j < 4; j++) {
                Frag bh, bl;
                const int so = j * 2048 + r * 128 + ((kc + g * 8) ^ xr);
                bh.u4 = *(const uint4*)(sBh + so);
                bl.u4 = *(const uint4*)(sBl + so);
#pragma unroll
                for (int i = 0; i < 2; i++)
                    acc[i][j] = __builtin_amdgcn_mfma_f32_16x16x32_bf16(a[i].b, bh.b, acc[i][j], 0, 0, 0);
#pragma unroll
                for (int i = 0; i < 2; i++)
                    acc[i][j] = __builtin_amdgcn_mfma_f32_16x16x32_bf16(a[i].b, bl.b, acc[i][j], 0, 0, 0);
            }
        }
    }
#pragma unroll
    for (int i = 0; i < 2; i++) {
#pragma unroll
        for (int j = 0; j < 4; j++) {
            int col = n0 + j * 16 + r;
            float bia = bias ? bias[col] : 0.f;
#pragma unroll
            for (int rr = 0; rr < 4; rr++) {
                int rowi = m0 + i * 16 + g * 4 + rr;
                size_t idx = (size_t)rowi * N + col;
                float v = acc[i][j][rr] + bia;
                if (resf) v += resf[idx];
                if (resx) {
                    int w = rowi / 49, n = rowi - w * 49;
                    int ii = w >> 5, jj = w & 31;
                    int p = n / 7, q = n - p * 7;
                    v += resx[(size_t)col * 50176 + (ii * 7 + p) * 224 + (jj * 7 + q)];
                }
                if (Yb) Yb[idx] = f2b(v);
                if (Yf) Yf[idx] = v;
            }
        }
    }
}

// Block attention (7x7, N=49). One block per (window, head). QKV bf16 in.
__global__ __launch_bounds__(256) void attn_block7(const unsigned short* __restrict__ qkv,
                                                   const float* __restrict__ table,
                                                   unsigned short* __restrict__ out) {
    __shared__ __align__(16) unsigned int sq[49 * 17], sk[49 * 17], sv[49 * 17];
    __shared__ float ssc[49 * 49];
    const int bx = blockIdx.x;
    const int w = bx >> 2, h = bx & 3;
    const int tid = threadIdx.x;
    const unsigned int* qsrc = (const unsigned int*)qkv;

    for (int u = tid; u < 784; u += 256) {
        int i = u >> 4, du = u & 15;
        size_t rb = (size_t)(w * 49 + i) * 192 + h * 16 + du;
        sq[i * 17 + du] = qsrc[rb];
        sk[i * 17 + du] = qsrc[rb + 64];
        sv[i * 17 + du] = qsrc[rb + 128];
    }
    __syncthreads();

    for (int e = tid; e < 2401; e += 256) {
        int i = e / 49, j = e - i * 49;
        const unsigned int* qp = sq + i * 17;
        const unsigned int* kp = sk + j * 17;
        float dot = 0.f;
#pragma unroll
        for (int u = 0; u < 16; u++) {
            unsigned int a = qp[u], b = kp[u];
            dot += b2f(a) * b2f(b) + b2f(a >> 16) * b2f(b >> 16);
        }
        int ih = i / 7, iw2 = i - ih * 7, jh = j / 7, jw2 = j - jh * 7;
        int idx = (ih - jh + 6) * 13 + (iw2 - jw2 + 6);
        ssc[e] = dot * 5.65685424949238f + table[idx * 4 + h];
    }
    __syncthreads();

    if (tid < 49) {
        float* row = ssc + tid * 49;
        float mx = -1e30f;
        for (int j = 0; j < 49; j++) mx = fmaxf(mx, row[j]);
        float sum = 0.f;
        for (int j = 0; j < 49; j++) { float p = __expf(row[j] - mx); row[j] = p; sum += p; }
        float inv = 1.f / sum;
        for (int j = 0; j < 49; j++) row[j] *= inv;
    }
    __syncthreads();

    unsigned int* outu = (unsigned int*)out;
    for (int e = tid; e < 784; e += 256) {
        int i = e >> 4, dp = e & 15;
        const float* pr = ssc + i * 49;
        float a0 = 0.f, a1 = 0.f;
        for (int j = 0; j < 49; j++) {
            float p = pr[j];
            unsigned int vv = sv[j * 17 + dp];
            a0 += p * b2f(vv);
            a1 += p * b2f(vv >> 16);
        }
        outu[(size_t)(w * 49 + i) * 64 + h * 16 + dp] =
            (unsigned int)f2b(a0) | ((unsigned int)f2b(a1) << 16);
    }
}

// ===========================================================================
// Grid attention v8 (REVERTED from v9: 128-key tiles regressed 113->167us with
// constant work counters => added stall; barrier count was not the limiter).
// v8 = v6 geometry (3136 blocks, 16 q-rows/wave) + XCD-chunked swizzle
// (FETCH 107->20MB, confirmed r14) + K/V register prefetch. 113us measured.
// ===========================================================================
__global__ __launch_bounds__(256) void attn_grid32(const unsigned short* __restrict__ qkv,
                                                   const float* __restrict__ tp,
                                                   unsigned short* __restrict__ out) {
    __shared__ __align__(16) unsigned short sK[64][40];
    __shared__ __align__(16) unsigned short sVt[32][72];     // [dim][pos]
    __shared__ __align__(16) unsigned short plds[4][16][72]; // [wave][qrow][pos]
    const int tid = threadIdx.x;
    const int lane = tid & 63;
    const int wid = tid >> 6;
    const int b = (blockIdx.x & 7) * 392 + (blockIdx.x >> 3);  // XCD-chunked, bijective
    const int w = b >> 6;
    const int h = (b >> 4) & 3;
    const int qb = b & 15;
    const int q0 = qb * 64 + wid * 16;
    const int c = lane & 15;
    const int g = lane >> 4;
    const size_t base = (size_t)w * 1024 * 384;
    const float scale2 = 5.65685424949238f * 1.4426950408889634f;  // sqrt(32)*log2(e)

    Frag qf;                                   // A-frag: Q[m=c][k=g*8..+7]
    qf.u4 = *(const uint4*)(qkv + base + (size_t)(q0 + c) * 384 + h * 32 + g * 8);

    const int qrow0 = q0 + g * 4;
    const float* tpl = tp + h * 3972 + ((qrow0 >> 5) + 31) * 63 + (qrow0 & 31) + 31 - c;

    float m_[4], l_[4];
    f32x4 o0 = {0.f, 0.f, 0.f, 0.f}, o1 = {0.f, 0.f, 0.f, 0.f};
#pragma unroll
    for (int rr = 0; rr < 4; rr++) { m_[rr] = 0.f; l_[rr] = 0.f; }

    const int skey = lane;
    const int sd = wid * 8;
    const int vpos = 4 * (skey & 15) + (skey >> 4);   // pos(k) = 4c + ch
    const unsigned short* kgp = qkv + base + 128 + h * 32 + sd;
    const unsigned short* vgp = qkv + base + 256 + h * 32 + sd;

    // prefetch tile 0
    Frag kcur, vcur, knxt, vnxt;
    kcur.u4 = *(const uint4*)(kgp + (size_t)skey * 384);
    vcur.u4 = *(const uint4*)(vgp + (size_t)skey * 384);
    knxt = kcur; vnxt = vcur;

    for (int jc = 0; jc < 1024; jc += 64) {
        // stage current tile; prior tile's reads protected by trailing barrier
        *(uint4*)(&sK[skey][sd]) = kcur.u4;
#pragma unroll
        for (int z = 0; z < 8; ++z) sVt[sd + z][vpos] = vcur.s[z];
        __syncthreads();
        // issue next tile's loads; consumed only after the next barrier
        if (jc < 960) {
            size_t roff = (size_t)(jc + 64 + skey) * 384;
            knxt.u4 = *(const uint4*)(kgp + roff);
            vnxt.u4 = *(const uint4*)(vgp + roff);
        }

        const float* tpj = tpl - (jc >> 5) * 63;
        f32x4 s4[4];
#pragma unroll
        for (int ch = 0; ch < 4; ++ch) {
            f32x4 cb = (f32x4)(*(const f32x4u*)(tpj - (ch >> 1) * 63 - (ch & 1) * 16));
            Frag kf;
            kf.u4 = *(const uint4*)(&sK[ch * 16 + c][g * 8]);
            s4[ch] = __builtin_amdgcn_mfma_f32_16x16x32_bf16(qf.b, kf.b, cb, 0, 0, 0);
        }
#pragma unroll
        for (int rr = 0; rr < 4; ++rr) {
            float s0 = s4[0][rr];
            float s1 = s4[1][rr];
            float s2 = s4[2][rr];
            float s3 = s4[3][rr];
            if (jc == 0) {
                float cm = fmaxf(fmaxf(s0, s1), fmaxf(s2, s3));
#pragma unroll
                for (int off = 1; off < 16; off <<= 1) cm = fmaxf(cm, __shfl_xor(cm, off, 64));
                m_[rr] = cm * scale2;          // running max kept pre-scaled
            }
            float mn = m_[rr];
            float p0 = exp2f(fmaf(s0, scale2, -mn));
            float p1 = exp2f(fmaf(s1, scale2, -mn));
            float p2 = exp2f(fmaf(s2, scale2, -mn));
            float p3 = exp2f(fmaf(s3, scale2, -mn));
            l_[rr] += (p0 + p1) + (p2 + p3);
            unsigned int* prow = (unsigned int*)(&plds[wid][g * 4 + rr][c * 4]);
            prow[0] = cvtpk(p0, p1);
            prow[1] = cvtpk(p2, p3);
        }
#pragma unroll
        for (int ch2 = 0; ch2 < 2; ++ch2) {
            Frag pf, vf0, vf1;
            pf.u4 = *(const uint4*)(&plds[wid][c][ch2 * 32 + g * 8]);
            vf0.u4 = *(const uint4*)(&sVt[c][ch2 * 32 + g * 8]);
            vf1.u4 = *(const uint4*)(&sVt[16 + c][ch2 * 32 + g * 8]);
            o0 = __builtin_amdgcn_mfma_f32_16x16x32_bf16(pf.b, vf0.b, o0, 0, 0, 0);
            o1 = __builtin_amdgcn_mfma_f32_16x16x32_bf16(pf.b, vf1.b, o1, 0, 0, 0);
        }
        __syncthreads();
        kcur = knxt; vcur = vnxt;
    }
#pragma unroll
    for (int rr = 0; rr < 4; rr++) {
        float ls = l_[rr];
#pragma unroll
        for (int off = 1; off < 16; off <<= 1) ls += __shfl_xor(ls, off, 64);
        float inv = 1.0f / ls;
        int row = q0 + g * 4 + rr;
        size_t ob = (size_t)(w * 1024 + row) * 128 + h * 32;
        out[ob + c] = f2b(o0[rr] * inv);
        out[ob + 16 + c] = f2b(o1[rr] * inv);
    }
}

// LayerNorm on fp32 input; writes bf16 (GEMM input) + fp32 (MLP shortcut).
__global__ __launch_bounds__(256) void ln_f(const float* __restrict__ in,
                                            const float* __restrict__ gam,
                                            const float* __restrict__ bet,
                                            unsigned short* __restrict__ outb,
                                            float* __restrict__ outf) {
    int token = blockIdx.x * 4 + (threadIdx.x >> 6);
    int lane = threadIdx.x & 63;
    float2 v = ((const float2*)in)[(size_t)token * 64 + lane];
    float s = v.x + v.y, s2 = v.x * v.x + v.y * v.y;
#pragma unroll
    for (int off = 1; off < 64; off <<= 1) {
        s += __shfl_xor(s, off, 64);
        s2 += __shfl_xor(s2, off, 64);
    }
    float mean = s * (1.f / 128.f);
    float var = s2 * (1.f / 128.f) - mean * mean;
    float inv = rsqrtf(var + 1e-5f);
    float2 gv = ((const float2*)gam)[lane];
    float2 bv = ((const float2*)bet)[lane];
    float y0 = (v.x - mean) * inv * gv.x + bv.x;
    float y1 = (v.y - mean) * inv * gv.y + bv.y;
    ((unsigned int*)outb)[(size_t)token * 64 + lane] =
        (unsigned int)f2b(y0) | ((unsigned int)f2b(y1) << 16);
    ((float2*)outf)[(size_t)token * 64 + lane] = make_float2(y0, y1);
}

// unbind(7)+transpose+partition(32): fp32 ya -> bf16 xb + fp32 xbf
__global__ __launch_bounds__(256) void remap_ab_f(const float* __restrict__ ya,
                                                  unsigned short* __restrict__ xb,
                                                  float* __restrict__ xbf) {
    int t = blockIdx.x * 256 + threadIdx.x;
    int c2 = t & 127;
    int tok = (t >> 7) & 1023;
    int W2 = t >> 17;
    int P = tok >> 5, Q = tok & 31;
    int I = W2 / 7, J = W2 - I * 7;
    int y = I * 32 + P, x2 = J * 32 + Q;
    int f = y * 28672 + x2 * 128 + c2;
    int c = f / 50176;
    int rm = f - c * 50176;
    int i = rm / 1568;
    int r2 = rm - i * 1568;
    int p = r2 / 224;
    int r3 = r2 - p * 224;
    int q = r3 >> 5, j = r3 & 31;
    float val = ya[((size_t)((i * 32 + j) * 49 + p * 7 + q)) * 128 + c];
    xb[t] = f2b(val);
    xbf[t] = val;
}

// unbind(32)+final transpose: fp32 yb -> fp32 out[1,128,224,224]
__global__ __launch_bounds__(256) void remap_out_f(const float* __restrict__ yb,
                                                   float* __restrict__ out) {
    int t = blockIdx.x * 256 + threadIdx.x;
    int c2 = t / 50176;
    int rem = t - c2 * 50176;
    int y = rem / 224;
    int x2 = rem - y * 224;
    int g = y * 28672 + x2 * 128 + c2;
    int c = g / 50176;
    int r = g - c * 50176;
    int I = r / 7168;
    int r2 = r - I * 7168;
    int P = r2 / 224;
    int r3 = r2 - P * 224;
    int Q = r3 / 7, J = r3 - Q * 7;
    out[t] = yb[((size_t)((I * 7 + J) * 1024 + P * 32 + Q)) * 128 + c];
}

// ===========================================================================
// FALLBACK PATH (proven round-7 scalar kernels; used if ws_size too small)
// ===========================================================================
__global__ __launch_bounds__(256) void remap_ab_s(const unsigned short* __restrict__ ya,
                                                  unsigned short* __restrict__ xb) {
    int t = blockIdx.x * 256 + threadIdx.x;
    int c2 = t & 127;
    int tok = (t >> 7) & 1023;
    int W2 = t >> 17;
    int P = tok >> 5, Q = tok & 31;
    int I = W2 / 7, J = W2 - I * 7;
    int y = I * 32 + P, x2 = J * 32 + Q;
    int f = y * 28672 + x2 * 128 + c2;
    int c = f / 50176;
    int rm = f - c * 50176;
    int i = rm / 1568;
    int r2 = rm - i * 1568;
    int p = r2 / 224;
    int r3 = r2 - p * 224;
    int q = r3 >> 5, j = r3 & 31;
    xb[t] = ya[((size_t)((i * 32 + j) * 49 + p * 7 + q)) * 128 + c];
}
__global__ __launch_bounds__(256) void remap_out_s(const unsigned short* __restrict__ yb,
                                                   float* __restrict__ out) {
    int t = blockIdx.x * 256 + threadIdx.x;
    int c2 = t / 50176;
    int rem = t - c2 * 50176;
    int y = rem / 224;
    int x2 = rem - y * 224;
    int g = y * 28672 + x2 * 128 + c2;
    int c = g / 50176;
    int r = g - c * 50176;
    int I = r / 7168;
    int r2 = r - I * 7168;
    int P = r2 / 224;
    int r3 = r2 - P * 224;
    int Q = r3 / 7, J = r3 - Q * 7;
    out[t] = b2f(yb[((size_t)((I * 7 + J) * 1024 + P * 32 + Q)) * 128 + c]);
}
__global__ __launch_bounds__(256) void gemm_w32(const unsigned short* __restrict__ X,
                                                const float* __restrict__ W,
                                                const float* __restrict__ bias,
                                                const unsigned short* __restrict__ res,
                                                unsigned short* __restrict__ Y,
                                                int M, int N, int K) {
    long long t = (long long)blockIdx.x * 256 + threadIdx.x;
    if (t >= (long long)M * N) return;
    int m = (int)(t / N);
    int n = (int)(t - (long long)m * N);
    const unsigned short* xr = X + (size_t)m * K;
    const float* wr = W + (size_t)n * K;
    float acc = bias ? bias[n] : 0.f;
    for (int k = 0; k < K; ++k) acc += b2f(xr[k]) * wr[k];
    if (res) acc += b2f(res[t]);
    Y[t] = f2b(acc);
}
__global__ __launch_bounds__(256) void attn_block7_fused(const unsigned short* __restrict__ xa,
                                                         const float* __restrict__ qw,
                                                         const float* __restrict__ table,
                                                         unsigned short* __restrict__ out) {
    __shared__ unsigned short sx[49 * 128];
    __shared__ float sq[49 * 32], sk[49 * 32], sv[49 * 32];
    __shared__ float ssc[49 * 49];
    const int bx = blockIdx.x;
    const int w = bx >> 2, h = bx & 3;
    const int tid = threadIdx.x;
    for (int u = tid; u < 6272; u += 256) sx[u] = xa[(size_t)(w * 49) * 128 + u];
    __syncthreads();
    for (int e = tid; e < 4704; e += 256) {
        int which = e / 1568;
        int rem = e - which * 1568;
        int n = rem >> 5, d = rem & 31;
        const float* wr = qw + (size_t)(which * 128 + h * 32 + d) * 128;
        const unsigned short* xr = sx + n * 128;
        float acc = 0.f;
        for (int k = 0; k < 128; ++k) acc += b2f(xr[k]) * wr[k];
        if (which == 0) sq[n * 32 + d] = acc;
        else if (which == 1) sk[n * 32 + d] = acc;
        else sv[n * 32 + d] = acc;
    }
    __syncthreads();
    for (int e = tid; e < 2401; e += 256) {
        int i = e / 49, j = e - i * 49;
        float dot = 0.f;
        for (int d = 0; d < 32; ++d) dot += sq[i * 32 + d] * sk[j * 32 + d];
        int ih = i / 7, iw2 = i - ih * 7, jh = j / 7, jw2 = j - jh * 7;
        int idx = (ih - jh + 6) * 13 + (iw2 - jw2 + 6);
        ssc[e] = dot * 5.65685424949238f + table[idx * 4 + h];
    }
    __syncthreads();
    if (tid < 49) {
        float* row = ssc + tid * 49;
        float mx = -1e30f;
        for (int j = 0; j < 49; j++) mx = fmaxf(mx, row[j]);
        float sum = 0.f;
        for (int j = 0; j < 49; j++) { float p = __expf(row[j] - mx); row[j] = p; sum += p; }
        float inv = 1.f / sum;
        for (int j = 0; j < 49; j++) row[j] *= inv;
    }
    __syncthreads();
    for (int e = tid; e < 1568; e += 256) {
        int i = e >> 5, d = e & 31;
        const float* pr = ssc + i * 49;
        float a = 0.f;
        for (int j = 0; j < 49; j++) a += pr[j] * sv[j * 32 + d];
        out[(size_t)(w * 49 + i) * 128 + h * 32 + d] = f2b(a);
    }
}
__global__ __launch_bounds__(256) void kv_head(const unsigned short* __restrict__ xa,
                                               const float* __restrict__ qw,
                                               int h,
                                               unsigned short* __restrict__ kvh) {
    int t = blockIdx.x * 256 + threadIdx.x;
    int tok = t >> 6, e = t & 63;
    int which = (e < 32) ? 1 : 2;
    int d = e & 31;
    const float* wr = qw + (size_t)(which * 128 + h * 32 + d) * 128;
    const unsigned short* xr = xa + (size_t)tok * 128;
    float acc = 0.f;
    for (int k = 0; k < 128; ++k) acc += b2f(xr[k]) * wr[k];
    kvh[t] = f2b(acc);
}
__global__ __launch_bounds__(256) void attn_grid_head(const unsigned short* __restrict__ xa,
                                                      const unsigned short* __restrict__ kvh,
                                                      const float* __restrict__ qw,
                                                      const float* __restrict__ table,
                                                      int h,
                                                      unsigned short* __restrict__ out) {
    __shared__ float sq[32];
    __shared__ float ss[1024];
    __shared__ float red[256];
    __shared__ float pvp[256];
    const int w = blockIdx.x >> 4;
    const int qg = blockIdx.x & 15;
    const int tid = threadIdx.x;
    const float scale = 5.65685424949238f;
    for (int qq = 0; qq < 64; ++qq) {
        const int qi = qg * 64 + qq;
        const int tok = w * 1024 + qi;
        if (tid < 32) {
            const float* wr = qw + (size_t)(h * 32 + tid) * 128;
            const unsigned short* xr = xa + (size_t)tok * 128;
            float acc = 0.f;
            for (int k = 0; k < 128; ++k) acc += b2f(xr[k]) * wr[k];
            sq[tid] = acc;
        }
        __syncthreads();
        const int ihq = qi >> 5, iwq = qi & 31;
        for (int k = tid; k < 1024; k += 256) {
            const unsigned short* kp = kvh + (size_t)(w * 1024 + k) * 64;
            float dot = 0.f;
            for (int d = 0; d < 32; ++d) dot += sq[d] * b2f(kp[d]);
            int jh2 = k >> 5, jw2 = k & 31;
            int idx = (ihq - jh2 + 31) * 63 + (iwq - jw2 + 31);
            ss[k] = dot * scale + table[idx * 4 + h];
        }
        __syncthreads();
        float m = fmaxf(fmaxf(ss[tid], ss[tid + 256]), fmaxf(ss[tid + 512], ss[tid + 768]));
        red[tid] = m;
        __syncthreads();
        for (int s = 128; s > 0; s >>= 1) {
            if (tid < s) red[tid] = fmaxf(red[tid], red[tid + s]);
            __syncthreads();
        }
        m = red[0];
        __syncthreads();
        float ps = 0.f;
        for (int k = tid; k < 1024; k += 256) {
            float p = __expf(ss[k] - m);
            ss[k] = p;
            ps += p;
        }
        red[tid] = ps;
        __syncthreads();
        for (int s = 128; s > 0; s >>= 1) {
            if (tid < s) red[tid] += red[tid + s];
            __syncthreads();
        }
        float l = red[0];
        int kc = tid >> 5, d = tid & 31;
        float a = 0.f;
        const unsigned short* vbase = kvh + (size_t)(w * 1024) * 64 + 32 + d;
        for (int k = kc * 128; k < kc * 128 + 128; ++k) a += ss[k] * b2f(vbase[(size_t)k * 64]);
        pvp[tid] = a;
        __syncthreads();
        if (tid < 32) {
            float o = 0.f;
            for (int c2 = 0; c2 < 8; ++c2) o += pvp[c2 * 32 + tid];
            out[(size_t)tok * 128 + h * 32 + tid] = f2b(o / l);
        }
        __syncthreads();
    }
}
__global__ __launch_bounds__(256) void mlp_fused(const unsigned short* __restrict__ xin,
                                                 const float* __restrict__ fc1w,
                                                 const float* __restrict__ fc1b,
                                                 const float* __restrict__ fc2w,
                                                 const float* __restrict__ fc2b,
                                                 unsigned short* __restrict__ out) {
    __shared__ float sxr[128];
    __shared__ float sh[512];
    const int tok = blockIdx.x;
    const int tid = threadIdx.x;
    if (tid < 128) sxr[tid] = b2f(xin[(size_t)tok * 128 + tid]);
    __syncthreads();
    for (int hh = tid; hh < 512; hh += 256) {
        const float* wr = fc1w + (size_t)hh * 128;
        float acc = fc1b[hh];
        for (int k = 0; k < 128; ++k) acc += sxr[k] * wr[k];
        sh[hh] = acc;
    }
    __syncthreads();
    if (tid < 128) {
        const float* wr = fc2w + (size_t)tid * 512;
        float acc = fc2b[tid];
        for (int k = 0; k < 512; ++k) acc += sh[k] * wr[k];
        out[(size_t)tok * 128 + tid] = f2b(acc + sxr[tid]);
    }
}
__global__ __launch_bounds__(256) void ln_k(const unsigned short* __restrict__ in,
                                            const float* __restrict__ gam,
                                            const float* __restrict__ bet,
                                            unsigned short* __restrict__ out) {
    int token = blockIdx.x * 4 + (threadIdx.x >> 6);
    int lane = threadIdx.x & 63;
    const unsigned int* row = (const unsigned int*)in + (size_t)token * 64;
    unsigned int v = row[lane];
    float x0 = b2f(v), x1 = b2f(v >> 16);
    float s = x0 + x1, s2 = x0 * x0 + x1 * x1;
#pragma unroll
    for (int off = 1; off < 64; off <<= 1) {
        s += __shfl_xor(s, off, 64);
        s2 += __shfl_xor(s2, off, 64);
    }
    float mean = s * (1.f / 128.f);
    float var = s2 * (1.f / 128.f) - mean * mean;
    float inv = rsqrtf(var + 1e-5f);
    float2 gv = ((const float2*)gam)[lane];
    float2 bv = ((const float2*)bet)[lane];
    float y0 = (x0 - mean) * inv * gv.x + bv.x;
    float y1 = (x1 - mean) * inv * gv.y + bv.y;
    ((unsigned int*)out)[(size_t)token * 64 + lane] =
        (unsigned int)f2b(y0) | ((unsigned int)f2b(y1) << 16);
}

// ===========================================================================
extern "C" void kernel_launch(void* const* d_in, const int* in_sizes, int n_in,
                              void* d_out, int out_size, void* d_ws, size_t ws_size,
                              hipStream_t stream) {
    (void)in_sizes; (void)n_in; (void)out_size;
    const float* x = (const float*)d_in[0];
    unsigned short* ws = (unsigned short*)d_ws;
    const int M = 50176;
    dim3 blk(256);
    #define F32(i) ((const float*)d_in[i])

    if (ws_size >= 117178368ull) {
        // ---------------- FAST PATH (MFMA, split weights) ----------------
        unsigned short* WHI = ws;
        unsigned short* WLO = ws + 393216;
        unsigned short* XA  = ws + 786432;
        unsigned short* AT  = ws + 7208960;
        unsigned short* Y2  = ws + 13631488;
        float*          R1  = (float*)(ws + 20054016);
        unsigned short* BIG = ws + 32899072;
        float*          Yf  = (float*)d_out;          // Y1f scratch
        float*          YOB = (float*)XA;             // stage-B fp32 out (XA∪AT)
        float*          TP  = (float*)d_out + 6400000; // grid-bias table (dead window)

        WPtrs wp = {F32(2), F32(3), F32(7), F32(9), F32(12), F32(13), F32(17), F32(19)};
        const size_t oqkv = 0, oproj = 49152, ofc1 = 65536, ofc2 = 131072;
        const size_t goff = 196608;

        conv_w2<<<1536, blk, 0, stream>>>(wp, WHI, WLO);
        gather_in<<<25088, blk, 0, stream>>>(x, XA);

        // ---- stage A ----
        gemm_bt<<<dim3(6, 196), blk, 0, stream>>>(XA, WHI + oqkv, WLO + oqkv, nullptr,
                                                  nullptr, nullptr, BIG, nullptr, M, 384, 128);
        attn_block7<<<4096, blk, 0, stream>>>(BIG, F32(1), AT);
        gemm_bt128<<<dim3(2, 392), blk, 0, stream>>>(AT, WHI + oproj, WLO + oproj, F32(4),
                                                     nullptr, x, nullptr, Yf, M, 128, 128);
        ln_f<<<12544, blk, 0, stream>>>(Yf, F32(5), F32(6), Y2, R1);
        gemm_bt<<<dim3(8, 196), blk, 0, stream>>>(Y2, WHI + ofc1, WLO + ofc1, F32(8),
                                                  nullptr, nullptr, BIG, nullptr, M, 512, 128);
        gemm_bt128<<<dim3(2, 392), blk, 0, stream>>>(BIG, WHI + ofc2, WLO + ofc2, F32(10),
                                                     R1, nullptr, nullptr, Yf, M, 128, 512);
        remap_ab_f<<<25088, blk, 0, stream>>>(Yf, XA, R1);

        // ---- stage B ----
        conv_bias<<<63, blk, 0, stream>>>(F32(11), TP);  // d_out tail is dead here
        gemm_bt<<<dim3(6, 196), blk, 0, stream>>>(XA, WHI + goff + oqkv, WLO + goff + oqkv,
                                                  nullptr, nullptr, nullptr, BIG, nullptr, M, 384, 128);
        attn_grid32<<<3136, blk, 0, stream>>>(BIG, TP, AT);
        gemm_bt128<<<dim3(2, 392), blk, 0, stream>>>(AT, WHI + goff + oproj, WLO + goff + oproj,
                                                     F32(14), R1, nullptr, nullptr, Yf, M, 128, 128);
        ln_f<<<12544, blk, 0, stream>>>(Yf, F32(15), F32(16), Y2, R1);
        gemm_bt<<<dim3(8, 196), blk, 0, stream>>>(Y2, WHI + goff + ofc1, WLO + goff + ofc1,
                                                  F32(18), nullptr, nullptr, BIG, nullptr, M, 512, 128);
        gemm_bt128<<<dim3(2, 392), blk, 0, stream>>>(BIG, WHI + goff + ofc2, WLO + goff + ofc2,
                                                     F32(20), R1, nullptr, nullptr, YOB, M, 128, 512);
        remap_out_f<<<25088, blk, 0, stream>>>(YOB, (float*)d_out);
    } else {
        // ---------------- FALLBACK (proven round-7 scalar path) ----------------
        unsigned short* XA  = ws;
        unsigned short* AT  = XA + 6422528;
        unsigned short* KVh = AT + 6422528;
        unsigned short* Yd  = (unsigned short*)d_out;

        gather_in<<<25088, blk, 0, stream>>>(x, XA);
        attn_block7_fused<<<4096, blk, 0, stream>>>(XA, F32(2), F32(1), AT);
        gemm_w32<<<25088, blk, 0, stream>>>(AT, F32(3), F32(4), XA, Yd, M, 128, 128);
        ln_k<<<12544, blk, 0, stream>>>(Yd, F32(5), F32(6), Yd);
        mlp_fused<<<50176, blk, 0, stream>>>(Yd, F32(7), F32(8), F32(9), F32(10), AT);
        remap_ab_s<<<25088, blk, 0, stream>>>(AT, XA);
        for (int h = 0; h < 4; ++h) {
            kv_head<<<12544, blk, 0, stream>>>(XA, F32(12), h, KVh);
            attn_grid_head<<<784, blk, 0, stream>>>(XA, KVh, F32(12), F32(11), h, AT);
        }
        gemm_w32<<<25088, blk, 0, stream>>>(AT, F32(13), F32(14), XA, Yd, M, 128, 128);
        ln_k<<<12544, blk, 0, stream>>>(Yd, F32(15), F32(16), Yd);
        mlp_fused<<<50176, blk, 0, stream>>>(Yd, F32(17), F32(18), F32(19), F32(20), AT);
        remap_out_s<<<25088, blk, 0, stream>>>(AT, (float*)d_out);
    }
    #undef F32
}